// Round 9
// baseline (484.081 us; speedup 1.0000x reference)
//
#include <hip/hip_runtime.h>

typedef unsigned short u16;
typedef __attribute__((ext_vector_type(8))) short short8;
typedef __attribute__((ext_vector_type(4))) float floatx4;

#define QSCALE 0.1803368801111204f  // log2(e)/8 : softmax kept in log2 domain

__device__ __forceinline__ u16 f2bf(float x) {
  union { float f; unsigned u; } un; un.f = x;
  unsigned r = un.u + 0x7fffu + ((un.u >> 16) & 1u);
  return (u16)(r >> 16);
}
__device__ __forceinline__ float bf2f(u16 h) {
  union { unsigned u; float f; } un; un.u = ((unsigned)h) << 16;
  return un.f;
}
__device__ __forceinline__ void gld16(const u16* g, u16* l) {
  __builtin_amdgcn_global_load_lds((__attribute__((address_space(1))) void*)g,
                                   (__attribute__((address_space(3))) void*)l, 16, 0, 0);
}

// ---------------- prep: weight transposes + WkvT + PE table, one dispatch ----------------
// segments: [0,1536) wtrans {W_Q,W_K,fw1}; [1536,1792) wkv; [1792,2048) pe_table.
__global__ __launch_bounds__(256) void prep_kernel(const float* __restrict__ W_Q,
                                                   const float* __restrict__ W_K,
                                                   const float* __restrict__ W_V,
                                                   const float* __restrict__ fw1,
                                                   u16* __restrict__ WqT, u16* __restrict__ WkT,
                                                   u16* __restrict__ F1T, u16* __restrict__ WkvT,
                                                   float* __restrict__ pet) {
  int L = blockIdx.x;
  int tid = threadIdx.y * 32 + threadIdx.x;
  if (L < 1536) {  // ---- weight transpose fp32->bf16: in (K,N) -> out (N,K)
    __shared__ float tile[32][33];
    const float* in;
    u16* out;
    int N, bx, by;
    if (L < 256) { in = W_Q; out = WqT; N = 512; bx = L & 15; by = L >> 4; }
    else if (L < 512) { L -= 256; in = W_K; out = WkT; N = 512; bx = L & 15; by = L >> 4; }
    else { L -= 512; in = fw1; out = F1T; N = 2048; bx = L & 63; by = L >> 6; }
    int tx = threadIdx.x, ty = threadIdx.y;
    int n0 = bx * 32, k0 = by * 32;
#pragma unroll
    for (int i = 0; i < 4; i++) {
      int kk = ty + i * 8;
      tile[kk][tx] = in[(size_t)(k0 + kk) * N + n0 + tx];
    }
    __syncthreads();
#pragma unroll
    for (int i = 0; i < 4; i++) {
      int nn = ty + i * 8;
      out[(size_t)(n0 + nn) * 512 + k0 + tx] = f2bf(tile[tx][nn]);
    }
  } else if (L < 1792) {  // ---- WkvT[n][d] = sum_e W_K[d][e]*W_V[e][n]
    L -= 1536;
    __shared__ float Kt[32][36];
    __shared__ float Vt[32][36];
    int nt = L & 15, dt = L >> 4;
    int n0 = nt * 32, d0 = dt * 32;
    int flat = tid * 4;
    int i4 = flat >> 5, j4 = flat & 31;
    int tn = tid & 15, td = tid >> 4;
    float acc00 = 0.f, acc01 = 0.f, acc10 = 0.f, acc11 = 0.f;
    for (int e0 = 0; e0 < 512; e0 += 32) {
      __syncthreads();
      *(float4*)&Kt[i4][j4] = *(const float4*)&W_K[(size_t)(d0 + i4) * 512 + e0 + j4];
      *(float4*)&Vt[i4][j4] = *(const float4*)&W_V[(size_t)(e0 + i4) * 512 + n0 + j4];
      __syncthreads();
#pragma unroll 8
      for (int e = 0; e < 32; e++) {
        float k0v = Kt[td * 2][e], k1v = Kt[td * 2 + 1][e];
        float v0 = Vt[e][tn * 2], v1 = Vt[e][tn * 2 + 1];
        acc00 += k0v * v0; acc01 += k0v * v1;
        acc10 += k1v * v0; acc11 += k1v * v1;
      }
    }
    size_t o = (size_t)(n0 + tn * 2) * 512 + d0 + td * 2;
    WkvT[o] = f2bf(acc00);
    WkvT[o + 1] = f2bf(acc10);
    WkvT[o + 512] = f2bf(acc01);
    WkvT[o + 513] = f2bf(acc11);
  } else {  // ---- PE table
    L -= 1792;
    int flat = (L * 256 + tid) * 4;
    int d0 = flat & 511;
    int t = flat >> 9;
    float pe[4];
#pragma unroll
    for (int i = 0; i < 4; i++) {
      int d = d0 + i;
      int j = (d < 256) ? d : d - 256;
      float f = exp2f((float)j * -0.05190512648f);  // -log2(10000)/256
      float arg = (float)t * f;
      pe[i] = (d < 256) ? cosf(arg) : sinf(arg);
    }
    *(float4*)(pet + flat) = *(const float4*)pe;
  }
}

// ---------------- PE add: q_in = bf16(q + pe), k_in = bf16(k + pe) ----------------
__global__ __launch_bounds__(256) void pe_add_kernel(const float* __restrict__ q,
                                                     const float* __restrict__ k,
                                                     const float* __restrict__ pet,
                                                     u16* __restrict__ qb, u16* __restrict__ kb) {
  size_t flat = ((size_t)blockIdx.x * 256 + threadIdx.x) * 4;
  const float4 qv = *(const float4*)(q + flat);
  const float4 kv = *(const float4*)(k + flat);
  const float4 pv = *(const float4*)(pet + (flat & 262143));  // (t*512+d) = flat mod 512*512
  u16 qo[4], ko[4];
  qo[0] = f2bf(qv.x + pv.x); qo[1] = f2bf(qv.y + pv.y);
  qo[2] = f2bf(qv.z + pv.z); qo[3] = f2bf(qv.w + pv.w);
  ko[0] = f2bf(kv.x + pv.x); ko[1] = f2bf(kv.y + pv.y);
  ko[2] = f2bf(kv.z + pv.z); ko[3] = f2bf(kv.w + pv.w);
  *(uint2*)(qb + flat) = *(const uint2*)qo;
  *(uint2*)(kb + flat) = *(const uint2*)ko;
}

// ======== shared 256x256 BK=64 2-barrier K-loop (round-7 proven schedule) ========
// Full-tile prefetch (A+B of kt+1, s_waitcnt vmcnt(8), never 0 mid-loop). 2 barriers/tile:
// one after the counted wait (staged data visible), one at region end (buffer reuse safety).
// The 24-ds_read / 64-MFMA region between them is left to the compiler's fine-grained
// lgkmcnt scheduling so LDS and matrix pipes overlap.
__device__ __forceinline__ void kloop256(const u16* __restrict__ A, const u16* __restrict__ Bt,
                                         int tm, int tn, u16* lds, int tid,
                                         floatx4 (&acc)[8][4]) {
  const int K = 512;
  const int lane = tid & 63, w = tid >> 6;
  const int quad = lane >> 4, cl = lane & 15;
  const int wm = w >> 2, wn = w & 3;
  const int srow = lane >> 3;
  const int sg = (lane & 7) ^ srow;
  const int cb = w * 4;

  {  // prologue: stage kt=0 into buf0
    u16* Ab = lds;
    u16* Bb = lds + 16384;
#pragma unroll
    for (int i = 0; i < 4; i++) {
      int cc = cb + i, row = cc * 8 + srow;
      gld16(A + ((size_t)(tm + row) * K + sg * 8), &Ab[cc * 512]);
    }
#pragma unroll
    for (int i = 0; i < 4; i++) {
      int cc = cb + i, row = cc * 8 + srow;
      gld16(Bt + ((size_t)(tn + row) * K + sg * 8), &Bb[cc * 512]);
    }
  }

  const int nk = K >> 6;
#pragma unroll 1
  for (int kt = 0; kt < nk; kt++) {
    u16* Ab = lds + (kt & 1) * 32768;
    u16* Bb = Ab + 16384;
    u16* An = lds + ((kt & 1) ^ 1) * 32768;
    u16* Bn = An + 16384;
    const bool pf = (kt + 1 < nk);
    const int k0n = (kt + 1) << 6;
    if (pf) {
#pragma unroll
      for (int i = 0; i < 4; i++) {
        int cc = cb + i, row = cc * 8 + srow;
        gld16(A + ((size_t)(tm + row) * K + k0n + sg * 8), &An[cc * 512]);
      }
#pragma unroll
      for (int i = 0; i < 4; i++) {
        int cc = cb + i, row = cc * 8 + srow;
        gld16(Bt + ((size_t)(tn + row) * K + k0n + sg * 8), &Bn[cc * 512]);
      }
      asm volatile("s_waitcnt vmcnt(8)" ::: "memory");  // stage(kt) landed; kt+1 in flight
    } else {
      asm volatile("s_waitcnt vmcnt(0)" ::: "memory");
    }
    __builtin_amdgcn_s_barrier();
    __builtin_amdgcn_sched_barrier(0);
    // ---- single free-scheduling region: 24 ds_read_b128 + 64 MFMA ----
    short8 a0[4][2], b0[2][2], b1[2][2], a1[4][2];
#pragma unroll
    for (int f = 0; f < 4; f++)
#pragma unroll
      for (int kh = 0; kh < 2; kh++)
        a0[f][kh] = *(const short8*)&Ab[(wm * 128 + f * 16 + cl) * 64 + ((((kh << 2) + quad)) ^ (cl & 7)) * 8];
#pragma unroll
    for (int n = 0; n < 2; n++)
#pragma unroll
      for (int kh = 0; kh < 2; kh++)
        b0[n][kh] = *(const short8*)&Bb[(wn * 64 + n * 16 + cl) * 64 + ((((kh << 2) + quad)) ^ (cl & 7)) * 8];
#pragma unroll
    for (int f = 0; f < 4; f++)
#pragma unroll
      for (int n = 0; n < 2; n++)
#pragma unroll
        for (int kh = 0; kh < 2; kh++)
          acc[f][n] = __builtin_amdgcn_mfma_f32_16x16x32_bf16(a0[f][kh], b0[n][kh], acc[f][n], 0, 0, 0);
#pragma unroll
    for (int n = 0; n < 2; n++)
#pragma unroll
      for (int kh = 0; kh < 2; kh++)
        b1[n][kh] = *(const short8*)&Bb[(wn * 64 + (n + 2) * 16 + cl) * 64 + ((((kh << 2) + quad)) ^ (cl & 7)) * 8];
#pragma unroll
    for (int f = 0; f < 4; f++)
#pragma unroll
      for (int n = 0; n < 2; n++)
#pragma unroll
        for (int kh = 0; kh < 2; kh++)
          acc[f][n + 2] = __builtin_amdgcn_mfma_f32_16x16x32_bf16(a0[f][kh], b1[n][kh], acc[f][n + 2], 0, 0, 0);
#pragma unroll
    for (int f = 0; f < 4; f++)
#pragma unroll
      for (int kh = 0; kh < 2; kh++)
        a1[f][kh] = *(const short8*)&Ab[(wm * 128 + (f + 4) * 16 + cl) * 64 + ((((kh << 2) + quad)) ^ (cl & 7)) * 8];
#pragma unroll
    for (int f = 0; f < 4; f++)
#pragma unroll
      for (int n = 0; n < 2; n++)
#pragma unroll
        for (int kh = 0; kh < 2; kh++)
          acc[f + 4][n + 2] = __builtin_amdgcn_mfma_f32_16x16x32_bf16(a1[f][kh], b1[n][kh], acc[f + 4][n + 2], 0, 0, 0);
#pragma unroll
    for (int f = 0; f < 4; f++)
#pragma unroll
      for (int n = 0; n < 2; n++)
#pragma unroll
        for (int kh = 0; kh < 2; kh++)
          acc[f + 4][n] = __builtin_amdgcn_mfma_f32_16x16x32_bf16(a1[f][kh], b0[n][kh], acc[f + 4][n], 0, 0, 0);
    __builtin_amdgcn_s_barrier();  // all reads consumed; buffer safe for kt+2 DMA
  }
}

// ---------------- projections: 256x256 tile, 2-barrier K-loop ----------------
// 3 segments: 0: qp = q_in@WqT^T; 1: kpb = k_in@WkT^T; 2: vT = (k_in@WkvT^T)^T per-head.
__global__ __launch_bounds__(512, 2) void proj_256(const u16* __restrict__ q_in,
                                                   const u16* __restrict__ k_in,
                                                   const u16* __restrict__ WqT,
                                                   const u16* __restrict__ WkT,
                                                   const u16* __restrict__ WkvT,
                                                   u16* __restrict__ qp,
                                                   u16* __restrict__ kpb,
                                                   u16* __restrict__ vTp) {
  __shared__ u16 lds[65536];  // 2 x (A 256x64 + B 256x64); seg2 reuses as Tr[128][264]
  const int tid = threadIdx.x;
  const int lane = tid & 63, w = tid >> 6;
  const int quad = lane >> 4, cl = lane & 15;
  const int wm = w >> 2, wn = w & 3;
  int L = blockIdx.x;
  const int seg = L >> 8;
  L &= 255;
  const u16* A = (seg == 0) ? q_in : k_in;
  const u16* Bt = (seg == 0) ? WqT : (seg == 1) ? WkT : WkvT;
  const int xcd = L & 7, s = L >> 3;
  const int nx = s & 1;     // 2 N-tiles (N=512)
  const int rgrp = s >> 1;  // 16 row-groups
  const int tm = (rgrp * 8 + xcd) * 256;
  const int tn = nx * 256;

  floatx4 acc[8][4] = {};
  kloop256(A, Bt, tm, tn, lds, tid, acc);

  if (seg < 2) {
    u16* C = (seg == 0) ? qp : kpb;
#pragma unroll
    for (int f = 0; f < 8; f++)
#pragma unroll
      for (int n = 0; n < 4; n++)
#pragma unroll
        for (int r = 0; r < 4; r++) {
          int row = tm + wm * 128 + f * 16 + quad * 4 + r;
          int col = tn + wn * 64 + n * 16 + cl;
          C[(size_t)row * 512 + col] = f2bf(acc[f][n][r]);
        }
  } else {
    // V^T per-head store via LDS transpose, two 128-col passes (Tr[128][264] = 66KB)
    const int b = tm >> 9, sbase = tm & 511;
#pragma unroll 1
    for (int p = 0; p < 2; p++) {
      __syncthreads();
      if ((wn >> 1) == p) {
        int cbase = (wn & 1) * 64;
#pragma unroll
        for (int f = 0; f < 8; f++)
#pragma unroll
          for (int n = 0; n < 4; n++)
#pragma unroll
            for (int r = 0; r < 4; r++) {
              int tc = cbase + n * 16 + cl;
              int row = wm * 128 + f * 16 + quad * 4 + r;
              lds[tc * 264 + row] = f2bf(acc[f][n][r]);
            }
      }
      __syncthreads();
      int col = tid >> 2;
      int e = tn + p * 128 + col;
      int h = e >> 6, d = e & 63;
      u16* dst = vTp + ((size_t)((b * 8 + h) * 64 + d) * 512 + sbase);
#pragma unroll
      for (int j = 0; j < 8; j++) {
        int chunk = (tid & 3) + j * 4;
        *(short8*)(dst + chunk * 8) = *(const short8*)&lds[col * 264 + chunk * 8];
      }
    }
  }
}

// ---------------- FFN1: 256x256 tile, 2-barrier K-loop; relu col-sum -> sums2 (no atomics)
__global__ __launch_bounds__(512, 2) void ffn1_256(const u16* __restrict__ A,
                                                   const u16* __restrict__ Bt,
                                                   float* __restrict__ sums2) {
  __shared__ u16 lds[65536];
  const int tid = threadIdx.x;
  const int lane = tid & 63, w = tid >> 6;
  const int quad = lane >> 4, cl = lane & 15;
  const int wm = w >> 2, wn = w & 3;
  int L = blockIdx.x;
  const int xcd = L & 7, s = L >> 3;
  const int nx = s & 7;
  const int rgrp = s >> 3;
  const int tm = (rgrp * 8 + xcd) * 256;
  const int tn = nx * 256;

  floatx4 acc[8][4] = {};
  kloop256(A, Bt, tm, tn, lds, tid, acc);

  float cs[4] = {0.f, 0.f, 0.f, 0.f};
#pragma unroll
  for (int f = 0; f < 8; f++)
#pragma unroll
    for (int n = 0; n < 4; n++)
#pragma unroll
      for (int r = 0; r < 4; r++) cs[n] += fmaxf(acc[f][n][r], 0.0f);
#pragma unroll
  for (int n = 0; n < 4; n++) {
    cs[n] += __shfl_xor(cs[n], 16);
    cs[n] += __shfl_xor(cs[n], 32);
  }
  // combine the two wm-waves in LDS (free after kloop's final barrier), single write
  float* red = (float*)lds;  // [2][256]
  if (quad == 0) {
#pragma unroll
    for (int n = 0; n < 4; n++) red[wm * 256 + wn * 64 + n * 16 + cl] = cs[n];
  }
  __syncthreads();
  if (tid < 256) {
    int mtile = tm >> 8;
    sums2[(size_t)mtile * 2048 + tn + tid] = red[tid] + red[256 + tid];
  }
}

// ---------------- ffn2 + mean finalize: outp[b][col] (single writer, no memset) ---------
// one block per b (512 threads, one col each): (sums2 rows 2b,2b+1) @ fw2 + attn colsums.
__global__ __launch_bounds__(512) void ffn2_final_kernel(const float* __restrict__ sums2,
                                                         const float* __restrict__ attnacc,
                                                         const float* __restrict__ fw2,
                                                         float* __restrict__ outp) {
  __shared__ float s[2048];
  int b = blockIdx.x, col = threadIdx.x;
  for (int i = col; i < 2048; i += 512)
    s[i] = sums2[(size_t)(2 * b) * 2048 + i] + sums2[(size_t)(2 * b + 1) * 2048 + i];
  __syncthreads();
  const float* w = fw2 + col;
  float a = 0.f;
#pragma unroll 8
  for (int f = 0; f < 2048; f++) a += s[f] * w[(size_t)f * 512];
  int h = col >> 6, c = col & 63;
  float att = 0.f;
  const float* ap = attnacc + ((size_t)(b * 8 + h) * 8) * 64 + c;
#pragma unroll
  for (int qt = 0; qt < 8; qt++) att += ap[qt * 64];
  outp[(size_t)b * 512 + col] = (a + att) * (1.0f / 512.0f);
}

// ---------------- flash attention + residual; colsum -> attnacc (no atomics) ------------
__global__ __launch_bounds__(256) void attn_kernel(const u16* __restrict__ qp, const u16* __restrict__ kp,
                                                   const u16* __restrict__ vT, const u16* __restrict__ qin,
                                                   u16* __restrict__ resout, const int* __restrict__ qlen,
                                                   const int* __restrict__ klen, float* __restrict__ attnacc) {
  __shared__ u16 KPu[8704];       // K tile (8192 u16) ∪ per-wave P scratch (4 x 2176 u16)
  __shared__ u16 Vlds[64 * 128];  // 16 KB
  __shared__ float Csum[4][64];
  int L = blockIdx.x;
  int xcd = L & 7;
  int idx = L >> 3;
  int qt = idx & 7;
  int g = xcd + (idx >> 3) * 8;  // (b*8+h)
  int h = g & 7, b = g >> 3;
  int tid = threadIdx.x, lane = tid & 63, w = tid >> 6;
  int quad = lane >> 4, cl = lane & 15;
  int kl = klen[b], ql = qlen[b];
  int q0 = qt * 64 + w * 16;
  float* aslot = attnacc + ((size_t)(g * 8 + qt)) * 64;

  if (qt * 64 >= ql) {
    int c = tid & 63, r0 = (tid >> 6) * 16;
    float sv = 0.f;
#pragma unroll
    for (int i = 0; i < 16; i++) {
      size_t idx2 = ((size_t)(b * 512 + qt * 64 + r0 + i) * 512) + h * 64 + c;
      u16 val = qin[idx2];
      resout[idx2] = val;
      sv += bf2f(val);
    }
    Csum[w][c] = sv;
    __syncthreads();
    if (tid < 64) aslot[tid] = Csum[0][tid] + Csum[1][tid] + Csum[2][tid] + Csum[3][tid];
    return;
  }
  bool wactive = q0 < ql;

  short8 qfrag[2];
#pragma unroll
  for (int ks = 0; ks < 2; ks++)
    qfrag[ks] = *(const short8*)(qp + ((size_t)(b * 512 + q0 + cl) * 512 + h * 64 + ks * 32 + quad * 8));
  const short8 ones8 = {(short)0x3F80, (short)0x3F80, (short)0x3F80, (short)0x3F80,
                        (short)0x3F80, (short)0x3F80, (short)0x3F80, (short)0x3F80};
  float m_r[4];  // running max in log2 units
  floatx4 o[4] = {};
  floatx4 lacc = {};
#pragma unroll
  for (int r = 0; r < 4; r++) m_r[r] = -3.0e38f;

  int nkt = (kl + 127) >> 7;
  for (int kt = 0; kt < nkt; kt++) {
    __syncthreads();  // A: prev PV + P reads done, safe to restage
#pragma unroll
    for (int i = 0; i < 4; i++) {  // K first (the 4 oldest vmem ops)
      int c = w * 4 + i;
      int row = c * 8 + (lane >> 3);
      int gc = (lane & 7) ^ (row & 7);
      gld16(kp + ((size_t)(b * 512 + kt * 128 + row) * 512 + h * 64 + gc * 8), &KPu[c * 512]);
    }
#pragma unroll
    for (int i = 0; i < 4; i++) {  // V second (may stay in flight through QK^T)
      int c = w * 4 + i;
      int row = c * 4 + (lane >> 4);
      int gc = (lane & 15) ^ (row & 7);
      gld16(vT + ((size_t)((b * 8 + h) * 64 + row) * 512 + kt * 128 + gc * 8), &Vlds[c * 512]);
    }
    asm volatile("s_waitcnt vmcnt(4)" ::: "memory");  // K landed; V still flying
    __builtin_amdgcn_s_barrier();                     // B': no full drain
    __builtin_amdgcn_sched_barrier(0);
    floatx4 sacc[8] = {};
    float mnew[4], alpha[4];
    if (wactive) {
      __builtin_amdgcn_s_setprio(1);
#pragma unroll
      for (int f = 0; f < 8; f++) {
        int krow = f * 16 + cl;
#pragma unroll
        for (int ks = 0; ks < 2; ks++) {
          int kc = ks * 4 + quad;
          short8 kf = *(const short8*)&KPu[krow * 64 + ((kc ^ (cl & 7)) * 8)];
          sacc[f] = __builtin_amdgcn_mfma_f32_16x16x32_bf16(qfrag[ks], kf, sacc[f], 0, 0, 0);
        }
      }
      __builtin_amdgcn_s_setprio(0);
#pragma unroll
      for (int r = 0; r < 4; r++) mnew[r] = m_r[r];
#pragma unroll
      for (int f = 0; f < 8; f++) {
        int key = kt * 128 + f * 16 + cl;
        bool ok = key < kl;
#pragma unroll
        for (int r = 0; r < 4; r++) {
          float v = ok ? sacc[f][r] * QSCALE : -4294967296.0f;  // log2-domain score
          sacc[f][r] = v;
          mnew[r] = fmaxf(mnew[r], v);
        }
      }
#pragma unroll
      for (int mk = 1; mk <= 8; mk <<= 1)
#pragma unroll
        for (int r = 0; r < 4; r++) mnew[r] = fmaxf(mnew[r], __shfl_xor(mnew[r], mk));
#pragma unroll
      for (int r = 0; r < 4; r++) {
        alpha[r] = exp2f(m_r[r] - mnew[r]);
        m_r[r] = mnew[r];
      }
    }
    __syncthreads();  // C: drains V loads; all K reads done, safe to overwrite with P
    if (wactive) {
      u16* P = &KPu[w * 2176];
#pragma unroll
      for (int f = 0; f < 8; f++)
#pragma unroll
        for (int r = 0; r < 4; r++) {
          float p = exp2f(sacc[f][r] - mnew[r]);
          P[(quad * 4 + r) * 136 + f * 16 + cl] = f2bf(p);
        }
#pragma unroll
      for (int r = 0; r < 4; r++) lacc[r] *= alpha[r];
#pragma unroll
      for (int fd = 0; fd < 4; fd++)
#pragma unroll
        for (int r = 0; r < 4; r++) o[fd][r] *= alpha[r];
      __builtin_amdgcn_s_setprio(1);
#pragma unroll
      for (int k2 = 0; k2 < 4; k2++) {
        short8 pf = *(const short8*)&P[cl * 136 + k2 * 32 + quad * 8];
        lacc = __builtin_amdgcn_mfma_f32_16x16x32_bf16(pf, ones8, lacc, 0, 0, 0);  // row-sum of P
#pragma unroll
        for (int fd = 0; fd < 4; fd++) {
          int vrow = fd * 16 + cl;
          int sc = k2 * 4 + quad;
          short8 vf = *(const short8*)&Vlds[vrow * 128 + ((sc ^ (cl & 7)) * 8)];
          o[fd] = __builtin_amdgcn_mfma_f32_16x16x32_bf16(pf, vf, o[fd], 0, 0, 0);
        }
      }
      __builtin_amdgcn_s_setprio(0);
    }
  }
  float colsum[4] = {0.f, 0.f, 0.f, 0.f};
#pragma unroll
  for (int fd = 0; fd < 4; fd++)
#pragma unroll
    for (int r = 0; r < 4; r++) {
      int q = q0 + quad * 4 + r;
      float v = o[fd][r] / lacc[r];
      if (q >= ql) v = 0.f;
      size_t idx2 = (size_t)(b * 512 + q) * 512 + h * 64 + fd * 16 + cl;
      v += bf2f(qin[idx2]);
      resout[idx2] = f2bf(v);
      colsum[fd] += v;
    }
#pragma unroll
  for (int fd = 0; fd < 4; fd++) {
    colsum[fd] += __shfl_xor(colsum[fd], 16);
    colsum[fd] += __shfl_xor(colsum[fd], 32);
  }
  if (quad == 0) {
#pragma unroll
    for (int fd = 0; fd < 4; fd++) Csum[w][fd * 16 + cl] = colsum[fd];
  }
  __syncthreads();
  if (tid < 64) aslot[tid] = Csum[0][tid] + Csum[1][tid] + Csum[2][tid] + Csum[3][tid];
}

// ---------------- launch ----------------
extern "C" void kernel_launch(void* const* d_in, const int* in_sizes, int n_in,
                              void* d_out, int out_size, void* d_ws, size_t ws_size,
                              hipStream_t stream) {
  const float* queries = (const float*)d_in[0];
  const float* keys = (const float*)d_in[1];
  const int* qlen = (const int*)d_in[2];
  const int* klen = (const int*)d_in[3];
  const float* W_Q = (const float*)d_in[4];
  const float* W_K = (const float*)d_in[5];
  const float* W_V = (const float*)d_in[6];
  const float* fw1 = (const float*)d_in[7];
  const float* fw2 = (const float*)d_in[8];
  float* outp = (float*)d_out;
  char* ws = (char*)d_ws;

  constexpr size_t SZ_W = 512 * 512 * 2;
  constexpr size_t SZ_F = 2048 * 512 * 2;
  constexpr size_t SZ_S = 128 * 2048 * 4;              // 1 MB fp32 per-Mtile relu col-sums
  constexpr size_t SZ_A = 4096 * 64 * 4;               // 1 MB fp32 attn per-(b,h,qt) col-sums
  constexpr size_t SZ_T = (size_t)64 * 512 * 512 * 2;  // 32 MB bf16
  size_t o_WqT = 0;
  size_t o_WkT = o_WqT + SZ_W;
  size_t o_Wkv = o_WkT + SZ_W;
  size_t o_F1T = o_Wkv + SZ_W;
  size_t o_SUM = o_F1T + SZ_F;
  size_t o_ATT = o_SUM + SZ_S;
  size_t o_ABCD = o_ATT + SZ_A;
  size_t o_E = o_ABCD + 4 * SZ_T;
  size_t NEED = o_E + SZ_T;
  if (ws_size < NEED) return;

  u16* WqT = (u16*)(ws + o_WqT);
  u16* WkT = (u16*)(ws + o_WkT);
  u16* WkvT = (u16*)(ws + o_Wkv);
  u16* F1T = (u16*)(ws + o_F1T);
  float* sums2 = (float*)(ws + o_SUM);
  float* attnacc = (float*)(ws + o_ATT);
  u16* q_in = (u16*)(ws + o_ABCD);
  u16* k_in = (u16*)(ws + o_ABCD + SZ_T);
  u16* qp = (u16*)(ws + o_ABCD + 2 * SZ_T);
  u16* kpb = (u16*)(ws + o_ABCD + 3 * SZ_T);
  u16* vT = (u16*)(ws + o_E);       // V^T lives in slot E
  float* pet = (float*)(ws + o_E);  // PE table aliases vT's first 1MB (dead until proj)
  u16* resb = k_in;                 // k_in dead after projections; attn never reads it

  prep_kernel<<<2048, dim3(32, 8), 0, stream>>>(W_Q, W_K, W_V, fw1, WqT, WkT, F1T, WkvT, pet);
  pe_add_kernel<<<16384, 256, 0, stream>>>(queries, keys, pet, q_in, k_in);

  // pipelined 256^2 triple projection (seg0 qp, seg1 kpb, seg2 vT)
  proj_256<<<768, 512, 0, stream>>>(q_in, k_in, WqT, WkT, WkvT, qp, kpb, vT);

  attn_kernel<<<4096, 256, 0, stream>>>(qp, kpb, vT, q_in, resb, qlen, klen, attnacc);

  // FFN1: relu col-sums only (h1 never materialized) — 256^2 pipelined GEMM, no atomics
  ffn1_256<<<1024, 512, 0, stream>>>(resb, F1T, sums2);
  // FFN2 + attn colsum + mean finalize — single writer of outp, no memset needed
  ffn2_final_kernel<<<64, 512, 0, stream>>>(sums2, attnacc, fw2, outp);
}

// Round 10
// 382.093 us; speedup vs baseline: 1.2669x; 1.2669x over previous
//
#include <hip/hip_runtime.h>

typedef unsigned short u16;
typedef __attribute__((ext_vector_type(8))) short short8;
typedef __attribute__((ext_vector_type(4))) float floatx4;

#define QSCALE 0.1803368801111204f  // log2(e)/8 : softmax kept in log2 domain

__device__ __forceinline__ u16 f2bf(float x) {
  union { float f; unsigned u; } un; un.f = x;
  unsigned r = un.u + 0x7fffu + ((un.u >> 16) & 1u);
  return (u16)(r >> 16);
}
__device__ __forceinline__ float bf2f(u16 h) {
  union { unsigned u; float f; } un; un.u = ((unsigned)h) << 16;
  return un.f;
}
__device__ __forceinline__ void gld16(const u16* g, u16* l) {
  __builtin_amdgcn_global_load_lds((__attribute__((address_space(1))) void*)g,
                                   (__attribute__((address_space(3))) void*)l, 16, 0, 0);
}

// ---------------- prep: weight transposes + WkvT + PE table, one dispatch ----------------
// segments: [0,1536) wtrans {W_Q,W_K,fw1}; [1536,1792) wkv; [1792,2048) pe_table.
__global__ __launch_bounds__(256) void prep_kernel(const float* __restrict__ W_Q,
                                                   const float* __restrict__ W_K,
                                                   const float* __restrict__ W_V,
                                                   const float* __restrict__ fw1,
                                                   u16* __restrict__ WqT, u16* __restrict__ WkT,
                                                   u16* __restrict__ F1T, u16* __restrict__ WkvT,
                                                   float* __restrict__ pet) {
  int L = blockIdx.x;
  int tid = threadIdx.y * 32 + threadIdx.x;
  if (L < 1536) {  // ---- weight transpose fp32->bf16: in (K,N) -> out (N,K)
    __shared__ float tile[32][33];
    const float* in;
    u16* out;
    int N, bx, by;
    if (L < 256) { in = W_Q; out = WqT; N = 512; bx = L & 15; by = L >> 4; }
    else if (L < 512) { L -= 256; in = W_K; out = WkT; N = 512; bx = L & 15; by = L >> 4; }
    else { L -= 512; in = fw1; out = F1T; N = 2048; bx = L & 63; by = L >> 6; }
    int tx = threadIdx.x, ty = threadIdx.y;
    int n0 = bx * 32, k0 = by * 32;
#pragma unroll
    for (int i = 0; i < 4; i++) {
      int kk = ty + i * 8;
      tile[kk][tx] = in[(size_t)(k0 + kk) * N + n0 + tx];
    }
    __syncthreads();
#pragma unroll
    for (int i = 0; i < 4; i++) {
      int nn = ty + i * 8;
      out[(size_t)(n0 + nn) * 512 + k0 + tx] = f2bf(tile[tx][nn]);
    }
  } else if (L < 1792) {  // ---- WkvT[n][d] = sum_e W_K[d][e]*W_V[e][n]
    L -= 1536;
    __shared__ float Kt[32][36];
    __shared__ float Vt[32][36];
    int nt = L & 15, dt = L >> 4;
    int n0 = nt * 32, d0 = dt * 32;
    int flat = tid * 4;
    int i4 = flat >> 5, j4 = flat & 31;
    int tn = tid & 15, td = tid >> 4;
    float acc00 = 0.f, acc01 = 0.f, acc10 = 0.f, acc11 = 0.f;
    for (int e0 = 0; e0 < 512; e0 += 32) {
      __syncthreads();
      *(float4*)&Kt[i4][j4] = *(const float4*)&W_K[(size_t)(d0 + i4) * 512 + e0 + j4];
      *(float4*)&Vt[i4][j4] = *(const float4*)&W_V[(size_t)(e0 + i4) * 512 + n0 + j4];
      __syncthreads();
#pragma unroll 8
      for (int e = 0; e < 32; e++) {
        float k0v = Kt[td * 2][e], k1v = Kt[td * 2 + 1][e];
        float v0 = Vt[e][tn * 2], v1 = Vt[e][tn * 2 + 1];
        acc00 += k0v * v0; acc01 += k0v * v1;
        acc10 += k1v * v0; acc11 += k1v * v1;
      }
    }
    size_t o = (size_t)(n0 + tn * 2) * 512 + d0 + td * 2;
    WkvT[o] = f2bf(acc00);
    WkvT[o + 1] = f2bf(acc10);
    WkvT[o + 512] = f2bf(acc01);
    WkvT[o + 513] = f2bf(acc11);
  } else {  // ---- PE table
    L -= 1792;
    int flat = (L * 256 + tid) * 4;
    int d0 = flat & 511;
    int t = flat >> 9;
    float pe[4];
#pragma unroll
    for (int i = 0; i < 4; i++) {
      int d = d0 + i;
      int j = (d < 256) ? d : d - 256;
      float f = exp2f((float)j * -0.05190512648f);  // -log2(10000)/256
      float arg = (float)t * f;
      pe[i] = (d < 256) ? cosf(arg) : sinf(arg);
    }
    *(float4*)(pet + flat) = *(const float4*)pe;
  }
}

// ---------------- PE add: q_in = bf16(q + pe), k_in = bf16(k + pe) ----------------
__global__ __launch_bounds__(256) void pe_add_kernel(const float* __restrict__ q,
                                                     const float* __restrict__ k,
                                                     const float* __restrict__ pet,
                                                     u16* __restrict__ qb, u16* __restrict__ kb) {
  size_t flat = ((size_t)blockIdx.x * 256 + threadIdx.x) * 4;
  const float4 qv = *(const float4*)(q + flat);
  const float4 kv = *(const float4*)(k + flat);
  const float4 pv = *(const float4*)(pet + (flat & 262143));  // (t*512+d) = flat mod 512*512
  u16 qo[4], ko[4];
  qo[0] = f2bf(qv.x + pv.x); qo[1] = f2bf(qv.y + pv.y);
  qo[2] = f2bf(qv.z + pv.z); qo[3] = f2bf(qv.w + pv.w);
  ko[0] = f2bf(kv.x + pv.x); ko[1] = f2bf(kv.y + pv.y);
  ko[2] = f2bf(kv.z + pv.z); ko[3] = f2bf(kv.w + pv.w);
  *(uint2*)(qb + flat) = *(const uint2*)qo;
  *(uint2*)(kb + flat) = *(const uint2*)ko;
}

// ======== shared 256x256 BK=64 2-barrier K-loop (round-7 proven schedule) ========
__device__ __forceinline__ void kloop256(const u16* __restrict__ A, const u16* __restrict__ Bt,
                                         int tm, int tn, u16* lds, int tid,
                                         floatx4 (&acc)[8][4]) {
  const int K = 512;
  const int lane = tid & 63, w = tid >> 6;
  const int quad = lane >> 4, cl = lane & 15;
  const int wm = w >> 2, wn = w & 3;
  const int srow = lane >> 3;
  const int sg = (lane & 7) ^ srow;
  const int cb = w * 4;

  {  // prologue: stage kt=0 into buf0
    u16* Ab = lds;
    u16* Bb = lds + 16384;
#pragma unroll
    for (int i = 0; i < 4; i++) {
      int cc = cb + i, row = cc * 8 + srow;
      gld16(A + ((size_t)(tm + row) * K + sg * 8), &Ab[cc * 512]);
    }
#pragma unroll
    for (int i = 0; i < 4; i++) {
      int cc = cb + i, row = cc * 8 + srow;
      gld16(Bt + ((size_t)(tn + row) * K + sg * 8), &Bb[cc * 512]);
    }
  }

  const int nk = K >> 6;
#pragma unroll 1
  for (int kt = 0; kt < nk; kt++) {
    u16* Ab = lds + (kt & 1) * 32768;
    u16* Bb = Ab + 16384;
    u16* An = lds + ((kt & 1) ^ 1) * 32768;
    u16* Bn = An + 16384;
    const bool pf = (kt + 1 < nk);
    const int k0n = (kt + 1) << 6;
    if (pf) {
#pragma unroll
      for (int i = 0; i < 4; i++) {
        int cc = cb + i, row = cc * 8 + srow;
        gld16(A + ((size_t)(tm + row) * K + k0n + sg * 8), &An[cc * 512]);
      }
#pragma unroll
      for (int i = 0; i < 4; i++) {
        int cc = cb + i, row = cc * 8 + srow;
        gld16(Bt + ((size_t)(tn + row) * K + k0n + sg * 8), &Bn[cc * 512]);
      }
      asm volatile("s_waitcnt vmcnt(8)" ::: "memory");  // stage(kt) landed; kt+1 in flight
    } else {
      asm volatile("s_waitcnt vmcnt(0)" ::: "memory");
    }
    __builtin_amdgcn_s_barrier();
    __builtin_amdgcn_sched_barrier(0);
    // ---- single free-scheduling region: 24 ds_read_b128 + 64 MFMA ----
    short8 a0[4][2], b0[2][2], b1[2][2], a1[4][2];
#pragma unroll
    for (int f = 0; f < 4; f++)
#pragma unroll
      for (int kh = 0; kh < 2; kh++)
        a0[f][kh] = *(const short8*)&Ab[(wm * 128 + f * 16 + cl) * 64 + ((((kh << 2) + quad)) ^ (cl & 7)) * 8];
#pragma unroll
    for (int n = 0; n < 2; n++)
#pragma unroll
      for (int kh = 0; kh < 2; kh++)
        b0[n][kh] = *(const short8*)&Bb[(wn * 64 + n * 16 + cl) * 64 + ((((kh << 2) + quad)) ^ (cl & 7)) * 8];
#pragma unroll
    for (int f = 0; f < 4; f++)
#pragma unroll
      for (int n = 0; n < 2; n++)
#pragma unroll
        for (int kh = 0; kh < 2; kh++)
          acc[f][n] = __builtin_amdgcn_mfma_f32_16x16x32_bf16(a0[f][kh], b0[n][kh], acc[f][n], 0, 0, 0);
#pragma unroll
    for (int n = 0; n < 2; n++)
#pragma unroll
      for (int kh = 0; kh < 2; kh++)
        b1[n][kh] = *(const short8*)&Bb[(wn * 64 + (n + 2) * 16 + cl) * 64 + ((((kh << 2) + quad)) ^ (cl & 7)) * 8];
#pragma unroll
    for (int f = 0; f < 4; f++)
#pragma unroll
      for (int n = 0; n < 2; n++)
#pragma unroll
        for (int kh = 0; kh < 2; kh++)
          acc[f][n + 2] = __builtin_amdgcn_mfma_f32_16x16x32_bf16(a0[f][kh], b1[n][kh], acc[f][n + 2], 0, 0, 0);
#pragma unroll
    for (int f = 0; f < 4; f++)
#pragma unroll
      for (int kh = 0; kh < 2; kh++)
        a1[f][kh] = *(const short8*)&Ab[(wm * 128 + (f + 4) * 16 + cl) * 64 + ((((kh << 2) + quad)) ^ (cl & 7)) * 8];
#pragma unroll
    for (int f = 0; f < 4; f++)
#pragma unroll
      for (int n = 0; n < 2; n++)
#pragma unroll
        for (int kh = 0; kh < 2; kh++)
          acc[f + 4][n + 2] = __builtin_amdgcn_mfma_f32_16x16x32_bf16(a1[f][kh], b1[n][kh], acc[f + 4][n + 2], 0, 0, 0);
#pragma unroll
    for (int f = 0; f < 4; f++)
#pragma unroll
      for (int n = 0; n < 2; n++)
#pragma unroll
        for (int kh = 0; kh < 2; kh++)
          acc[f + 4][n] = __builtin_amdgcn_mfma_f32_16x16x32_bf16(a1[f][kh], b0[n][kh], acc[f + 4][n], 0, 0, 0);
    __builtin_amdgcn_s_barrier();  // all reads consumed; buffer safe for kt+2 DMA
  }
}

// ---------------- projections: 256x256 tile, 2-barrier K-loop ----------------
// 3 segments: 0: qp = q_in@WqT^T; 1: kpb = k_in@WkT^T; 2: vT = (k_in@WkvT^T)^T per-head.
__global__ __launch_bounds__(512, 2) void proj_256(const u16* __restrict__ q_in,
                                                   const u16* __restrict__ k_in,
                                                   const u16* __restrict__ WqT,
                                                   const u16* __restrict__ WkT,
                                                   const u16* __restrict__ WkvT,
                                                   u16* __restrict__ qp,
                                                   u16* __restrict__ kpb,
                                                   u16* __restrict__ vTp) {
  __shared__ u16 lds[65536];  // 2 x (A 256x64 + B 256x64); seg2 reuses as Tr[128][264]
  const int tid = threadIdx.x;
  const int lane = tid & 63, w = tid >> 6;
  const int quad = lane >> 4, cl = lane & 15;
  const int wm = w >> 2, wn = w & 3;
  int L = blockIdx.x;
  const int seg = L >> 8;
  L &= 255;
  const u16* A = (seg == 0) ? q_in : k_in;
  const u16* Bt = (seg == 0) ? WqT : (seg == 1) ? WkT : WkvT;
  const int xcd = L & 7, s = L >> 3;
  const int nx = s & 1;     // 2 N-tiles (N=512)
  const int rgrp = s >> 1;  // 16 row-groups
  const int tm = (rgrp * 8 + xcd) * 256;
  const int tn = nx * 256;

  floatx4 acc[8][4] = {};
  kloop256(A, Bt, tm, tn, lds, tid, acc);

  if (seg < 2) {
    u16* C = (seg == 0) ? qp : kpb;
#pragma unroll
    for (int f = 0; f < 8; f++)
#pragma unroll
      for (int n = 0; n < 4; n++)
#pragma unroll
        for (int r = 0; r < 4; r++) {
          int row = tm + wm * 128 + f * 16 + quad * 4 + r;
          int col = tn + wn * 64 + n * 16 + cl;
          C[(size_t)row * 512 + col] = f2bf(acc[f][n][r]);
        }
  } else {
    // V^T per-head store via LDS transpose, two 128-col passes (Tr[128][264] = 66KB)
    const int b = tm >> 9, sbase = tm & 511;
#pragma unroll 1
    for (int p = 0; p < 2; p++) {
      __syncthreads();
      if ((wn >> 1) == p) {
        int cbase = (wn & 1) * 64;
#pragma unroll
        for (int f = 0; f < 8; f++)
#pragma unroll
          for (int n = 0; n < 4; n++)
#pragma unroll
            for (int r = 0; r < 4; r++) {
              int tc = cbase + n * 16 + cl;
              int row = wm * 128 + f * 16 + quad * 4 + r;
              lds[tc * 264 + row] = f2bf(acc[f][n][r]);
            }
      }
      __syncthreads();
      int col = tid >> 2;
      int e = tn + p * 128 + col;
      int h = e >> 6, d = e & 63;
      u16* dst = vTp + ((size_t)((b * 8 + h) * 64 + d) * 512 + sbase);
#pragma unroll
      for (int j = 0; j < 8; j++) {
        int chunk = (tid & 3) + j * 4;
        *(short8*)(dst + chunk * 8) = *(const short8*)&lds[col * 264 + chunk * 8];
      }
    }
  }
}

// ---------------- FFN1: 256x256 tile, 2-barrier K-loop; relu col-sum -> sums2 (no atomics)
__global__ __launch_bounds__(512, 2) void ffn1_256(const u16* __restrict__ A,
                                                   const u16* __restrict__ Bt,
                                                   float* __restrict__ sums2) {
  __shared__ u16 lds[65536];
  const int tid = threadIdx.x;
  const int lane = tid & 63, w = tid >> 6;
  const int quad = lane >> 4, cl = lane & 15;
  const int wm = w >> 2, wn = w & 3;
  int L = blockIdx.x;
  const int xcd = L & 7, s = L >> 3;
  const int nx = s & 7;
  const int rgrp = s >> 3;
  const int tm = (rgrp * 8 + xcd) * 256;
  const int tn = nx * 256;

  floatx4 acc[8][4] = {};
  kloop256(A, Bt, tm, tn, lds, tid, acc);

  float cs[4] = {0.f, 0.f, 0.f, 0.f};
#pragma unroll
  for (int f = 0; f < 8; f++)
#pragma unroll
    for (int n = 0; n < 4; n++)
#pragma unroll
      for (int r = 0; r < 4; r++) cs[n] += fmaxf(acc[f][n][r], 0.0f);
#pragma unroll
  for (int n = 0; n < 4; n++) {
    cs[n] += __shfl_xor(cs[n], 16);
    cs[n] += __shfl_xor(cs[n], 32);
  }
  // combine the two wm-waves in LDS (free after kloop's final barrier), single write
  float* red = (float*)lds;  // [2][256]
  if (quad == 0) {
#pragma unroll
    for (int n = 0; n < 4; n++) red[wm * 256 + wn * 64 + n * 16 + cl] = cs[n];
  }
  __syncthreads();
  if (tid < 256) {
    int mtile = tm >> 8;
    sums2[(size_t)mtile * 2048 + tn + tid] = red[tid] + red[256 + tid];
  }
}

// ---------------- ffn2 via mean-commutation, f-split 16 ways; fs==0 folds attn colsums ----
__global__ __launch_bounds__(256) void ffn2_mean_kernel(const float* __restrict__ sums2,
                                                        const float* __restrict__ attnacc,
                                                        const float* __restrict__ fw2,
                                                        float* __restrict__ outp) {
  __shared__ float s[128];
  int fs = blockIdx.x & 15, b = blockIdx.x >> 4;
  int tid = threadIdx.x;
  if (tid < 128) {
    int i = fs * 128 + tid;
    s[tid] = sums2[(size_t)(2 * b) * 2048 + i] + sums2[(size_t)(2 * b + 1) * 2048 + i];
  }
  __syncthreads();
  const float* w = fw2 + (size_t)(fs * 128) * 512;
  float a0 = 0.f, a1 = 0.f;
#pragma unroll 4
  for (int f = 0; f < 128; f++) {
    float sv = s[f];
    a0 += sv * w[(size_t)f * 512 + tid];
    a1 += sv * w[(size_t)f * 512 + 256 + tid];
  }
  if (fs == 0) {  // fold attention+residual colsums exactly once per (b,col)
    int h0 = tid >> 6, c0 = tid & 63;
    int col1 = tid + 256, h1 = col1 >> 6, c1 = col1 & 63;
    const float* ap0 = attnacc + ((size_t)(b * 8 + h0) * 8) * 64 + c0;
    const float* ap1 = attnacc + ((size_t)(b * 8 + h1) * 8) * 64 + c1;
#pragma unroll
    for (int qt = 0; qt < 8; qt++) {
      a0 += ap0[qt * 64];
      a1 += ap1[qt * 64];
    }
  }
  atomicAdd(outp + b * 512 + tid, a0 * (1.0f / 512.0f));
  atomicAdd(outp + b * 512 + 256 + tid, a1 * (1.0f / 512.0f));
}

// ---------------- flash attention + residual; colsum -> attnacc (no atomics) ------------
__global__ __launch_bounds__(256) void attn_kernel(const u16* __restrict__ qp, const u16* __restrict__ kp,
                                                   const u16* __restrict__ vT, const u16* __restrict__ qin,
                                                   u16* __restrict__ resout, const int* __restrict__ qlen,
                                                   const int* __restrict__ klen, float* __restrict__ attnacc) {
  __shared__ u16 KPu[8704];       // K tile (8192 u16) ∪ per-wave P scratch (4 x 2176 u16)
  __shared__ u16 Vlds[64 * 128];  // 16 KB
  __shared__ float Csum[4][64];
  int L = blockIdx.x;
  int xcd = L & 7;
  int idx = L >> 3;
  int qt = idx & 7;
  int g = xcd + (idx >> 3) * 8;  // (b*8+h)
  int h = g & 7, b = g >> 3;
  int tid = threadIdx.x, lane = tid & 63, w = tid >> 6;
  int quad = lane >> 4, cl = lane & 15;
  int kl = klen[b], ql = qlen[b];
  int q0 = qt * 64 + w * 16;
  float* aslot = attnacc + ((size_t)(g * 8 + qt)) * 64;

  if (qt * 64 >= ql) {
    int c = tid & 63, r0 = (tid >> 6) * 16;
    float sv = 0.f;
#pragma unroll
    for (int i = 0; i < 16; i++) {
      size_t idx2 = ((size_t)(b * 512 + qt * 64 + r0 + i) * 512) + h * 64 + c;
      u16 val = qin[idx2];
      resout[idx2] = val;
      sv += bf2f(val);
    }
    Csum[w][c] = sv;
    __syncthreads();
    if (tid < 64) aslot[tid] = Csum[0][tid] + Csum[1][tid] + Csum[2][tid] + Csum[3][tid];
    return;
  }
  bool wactive = q0 < ql;

  short8 qfrag[2];
#pragma unroll
  for (int ks = 0; ks < 2; ks++)
    qfrag[ks] = *(const short8*)(qp + ((size_t)(b * 512 + q0 + cl) * 512 + h * 64 + ks * 32 + quad * 8));
  const short8 ones8 = {(short)0x3F80, (short)0x3F80, (short)0x3F80, (short)0x3F80,
                        (short)0x3F80, (short)0x3F80, (short)0x3F80, (short)0x3F80};
  float m_r[4];  // running max in log2 units
  floatx4 o[4] = {};
  floatx4 lacc = {};
#pragma unroll
  for (int r = 0; r < 4; r++) m_r[r] = -3.0e38f;

  int nkt = (kl + 127) >> 7;
  for (int kt = 0; kt < nkt; kt++) {
    __syncthreads();  // A: prev PV + P reads done, safe to restage
#pragma unroll
    for (int i = 0; i < 4; i++) {  // K first (the 4 oldest vmem ops)
      int c = w * 4 + i;
      int row = c * 8 + (lane >> 3);
      int gc = (lane & 7) ^ (row & 7);
      gld16(kp + ((size_t)(b * 512 + kt * 128 + row) * 512 + h * 64 + gc * 8), &KPu[c * 512]);
    }
#pragma unroll
    for (int i = 0; i < 4; i++) {  // V second (may stay in flight through QK^T)
      int c = w * 4 + i;
      int row = c * 4 + (lane >> 4);
      int gc = (lane & 15) ^ (row & 7);
      gld16(vT + ((size_t)((b * 8 + h) * 64 + row) * 512 + kt * 128 + gc * 8), &Vlds[c * 512]);
    }
    asm volatile("s_waitcnt vmcnt(4)" ::: "memory");  // K landed; V still flying
    __builtin_amdgcn_s_barrier();                     // B': no full drain
    __builtin_amdgcn_sched_barrier(0);
    floatx4 sacc[8] = {};
    float mnew[4], alpha[4];
    if (wactive) {
      __builtin_amdgcn_s_setprio(1);
#pragma unroll
      for (int f = 0; f < 8; f++) {
        int krow = f * 16 + cl;
#pragma unroll
        for (int ks = 0; ks < 2; ks++) {
          int kc = ks * 4 + quad;
          short8 kf = *(const short8*)&KPu[krow * 64 + ((kc ^ (cl & 7)) * 8)];
          sacc[f] = __builtin_amdgcn_mfma_f32_16x16x32_bf16(qfrag[ks], kf, sacc[f], 0, 0, 0);
        }
      }
      __builtin_amdgcn_s_setprio(0);
#pragma unroll
      for (int r = 0; r < 4; r++) mnew[r] = m_r[r];
#pragma unroll
      for (int f = 0; f < 8; f++) {
        int key = kt * 128 + f * 16 + cl;
        bool ok = key < kl;
#pragma unroll
        for (int r = 0; r < 4; r++) {
          float v = ok ? sacc[f][r] * QSCALE : -4294967296.0f;  // log2-domain score
          sacc[f][r] = v;
          mnew[r] = fmaxf(mnew[r], v);
        }
      }
#pragma unroll
      for (int mk = 1; mk <= 8; mk <<= 1)
#pragma unroll
        for (int r = 0; r < 4; r++) mnew[r] = fmaxf(mnew[r], __shfl_xor(mnew[r], mk));
#pragma unroll
      for (int r = 0; r < 4; r++) {
        alpha[r] = exp2f(m_r[r] - mnew[r]);
        m_r[r] = mnew[r];
      }
    }
    __syncthreads();  // C: drains V loads; all K reads done, safe to overwrite with P
    if (wactive) {
      u16* P = &KPu[w * 2176];
#pragma unroll
      for (int f = 0; f < 8; f++)
#pragma unroll
        for (int r = 0; r < 4; r++) {
          float p = exp2f(sacc[f][r] - mnew[r]);
          P[(quad * 4 + r) * 136 + f * 16 + cl] = f2bf(p);
        }
#pragma unroll
      for (int r = 0; r < 4; r++) lacc[r] *= alpha[r];
#pragma unroll
      for (int fd = 0; fd < 4; fd++)
#pragma unroll
        for (int r = 0; r < 4; r++) o[fd][r] *= alpha[r];
      __builtin_amdgcn_s_setprio(1);
#pragma unroll
      for (int k2 = 0; k2 < 4; k2++) {
        short8 pf = *(const short8*)&P[cl * 136 + k2 * 32 + quad * 8];
        lacc = __builtin_amdgcn_mfma_f32_16x16x32_bf16(pf, ones8, lacc, 0, 0, 0);  // row-sum of P
#pragma unroll
        for (int fd = 0; fd < 4; fd++) {
          int vrow = fd * 16 + cl;
          int sc = k2 * 4 + quad;
          short8 vf = *(const short8*)&Vlds[vrow * 128 + ((sc ^ (cl & 7)) * 8)];
          o[fd] = __builtin_amdgcn_mfma_f32_16x16x32_bf16(pf, vf, o[fd], 0, 0, 0);
        }
      }
      __builtin_amdgcn_s_setprio(0);
    }
  }
  float colsum[4] = {0.f, 0.f, 0.f, 0.f};
#pragma unroll
  for (int fd = 0; fd < 4; fd++)
#pragma unroll
    for (int r = 0; r < 4; r++) {
      int q = q0 + quad * 4 + r;
      float v = o[fd][r] / lacc[r];
      if (q >= ql) v = 0.f;
      size_t idx2 = (size_t)(b * 512 + q) * 512 + h * 64 + fd * 16 + cl;
      v += bf2f(qin[idx2]);
      resout[idx2] = f2bf(v);
      colsum[fd] += v;
    }
#pragma unroll
  for (int fd = 0; fd < 4; fd++) {
    colsum[fd] += __shfl_xor(colsum[fd], 16);
    colsum[fd] += __shfl_xor(colsum[fd], 32);
  }
  if (quad == 0) {
#pragma unroll
    for (int fd = 0; fd < 4; fd++) Csum[w][fd * 16 + cl] = colsum[fd];
  }
  __syncthreads();
  if (tid < 64) aslot[tid] = Csum[0][tid] + Csum[1][tid] + Csum[2][tid] + Csum[3][tid];
}

// ---------------- launch ----------------
extern "C" void kernel_launch(void* const* d_in, const int* in_sizes, int n_in,
                              void* d_out, int out_size, void* d_ws, size_t ws_size,
                              hipStream_t stream) {
  const float* queries = (const float*)d_in[0];
  const float* keys = (const float*)d_in[1];
  const int* qlen = (const int*)d_in[2];
  const int* klen = (const int*)d_in[3];
  const float* W_Q = (const float*)d_in[4];
  const float* W_K = (const float*)d_in[5];
  const float* W_V = (const float*)d_in[6];
  const float* fw1 = (const float*)d_in[7];
  const float* fw2 = (const float*)d_in[8];
  float* outp = (float*)d_out;
  char* ws = (char*)d_ws;

  constexpr size_t SZ_W = 512 * 512 * 2;
  constexpr size_t SZ_F = 2048 * 512 * 2;
  constexpr size_t SZ_S = 128 * 2048 * 4;              // 1 MB fp32 per-Mtile relu col-sums
  constexpr size_t SZ_A = 4096 * 64 * 4;               // 1 MB fp32 attn per-(b,h,qt) col-sums
  constexpr size_t SZ_T = (size_t)64 * 512 * 512 * 2;  // 32 MB bf16
  size_t o_WqT = 0;
  size_t o_WkT = o_WqT + SZ_W;
  size_t o_Wkv = o_WkT + SZ_W;
  size_t o_F1T = o_Wkv + SZ_W;
  size_t o_SUM = o_F1T + SZ_F;
  size_t o_ATT = o_SUM + SZ_S;
  size_t o_ABCD = o_ATT + SZ_A;
  size_t o_E = o_ABCD + 4 * SZ_T;
  size_t NEED = o_E + SZ_T;
  if (ws_size < NEED) return;

  u16* WqT = (u16*)(ws + o_WqT);
  u16* WkT = (u16*)(ws + o_WkT);
  u16* WkvT = (u16*)(ws + o_Wkv);
  u16* F1T = (u16*)(ws + o_F1T);
  float* sums2 = (float*)(ws + o_SUM);
  float* attnacc = (float*)(ws + o_ATT);
  u16* q_in = (u16*)(ws + o_ABCD);
  u16* k_in = (u16*)(ws + o_ABCD + SZ_T);
  u16* qp = (u16*)(ws + o_ABCD + 2 * SZ_T);
  u16* kpb = (u16*)(ws + o_ABCD + 3 * SZ_T);
  u16* vT = (u16*)(ws + o_E);       // V^T lives in slot E
  float* pet = (float*)(ws + o_E);  // PE table aliases vT's first 1MB (dead until proj)
  u16* resb = k_in;                 // k_in dead after projections; attn never reads it

  hipMemsetAsync(d_out, 0, (size_t)out_size * sizeof(float), stream);

  prep_kernel<<<2048, dim3(32, 8), 0, stream>>>(W_Q, W_K, W_V, fw1, WqT, WkT, F1T, WkvT, pet);
  pe_add_kernel<<<16384, 256, 0, stream>>>(queries, keys, pet, q_in, k_in);

  // pipelined 256^2 triple projection (seg0 qp, seg1 kpb, seg2 vT)
  proj_256<<<768, 512, 0, stream>>>(q_in, k_in, WqT, WkT, WkvT, qp, kpb, vT);

  attn_kernel<<<4096, 256, 0, stream>>>(qp, kpb, vT, q_in, resb, qlen, klen, attnacc);

  // FFN1: relu col-sums only (h1 never materialized) — 256^2 pipelined GEMM, no atomics
  ffn1_256<<<1024, 512, 0, stream>>>(resb, F1T, sums2);
  // FFN2 collapsed to (sums/512) @ fw2, f-split 16 ways; fs==0 folds attn colsums
  ffn2_mean_kernel<<<1024, 256, 0, stream>>>(sums2, attnacc, fw2, outp);
}